// Round 3
// baseline (174.570 us; speedup 1.0000x reference)
//
#include <hip/hip_runtime.h>
#include <hip/hip_bf16.h>
#include <math.h>

// ---------------------------------------------------------------------------
// Math note: softmax(A, axis=2) then sum(A, axis=2, keepdims=True) * V == V.
// Pipeline: X1 = LN(X + X@Wv + bv); out = LN(X1 + relu(X1@W1+b1)@W2 + b2)
//
// Round-3: all GEMMs use the 256x256 8-phase template (T2 swizzle + T3/T4
// counted-vmcnt pipeline + T5 setprio), 512 thr / 8 waves, LDS 128 KB.
//  - GEMM1 (8192x768x768)  split-K x2 -> bf16 partials P1, reduce in LN1
//  - GEMM2 (8192x3072x768) full K, relu+bias epilogue
//  - GEMM3 (8192x768x3072) split-K x2 -> bf16 partials P3, reduce in LN2
// ---------------------------------------------------------------------------

typedef __bf16 bf16x8 __attribute__((ext_vector_type(8)));
typedef float f32x4 __attribute__((ext_vector_type(4)));

__device__ inline void gload_lds16(const __hip_bfloat16* g, void* lds) {
  __builtin_amdgcn_global_load_lds(
      (const __attribute__((address_space(1))) void*)g,
      (__attribute__((address_space(3))) void*)lds, 16, 0, 0);
}

__device__ inline float bf2f(unsigned short u) {
  union { unsigned int i; float f; } x;
  x.i = ((unsigned int)u) << 16;
  return x.f;
}

#define BARRIER() asm volatile("s_barrier" ::: "memory")

// C = A(MxK) @ Bt(NxK)^T over K-range [z*Ksub, (z+1)*Ksub), 256x256 tile.
// EPI==0: raw bf16 partial at C + z*M*N;  EPI==2: +bias, relu -> bf16
template <int EPI>
__global__ __launch_bounds__(512, 2) void gemm256(
    const __hip_bfloat16* __restrict__ A, const __hip_bfloat16* __restrict__ Bt,
    __hip_bfloat16* __restrict__ C, const float* __restrict__ bias,
    int M, int N, int K, int Ksub, int mB, int nB) {
  // LDS: A [2buf][2half][128][64]bf16 = 64KB, then B same = 64KB.
  __shared__ __align__(16) char smem[131072];

  // XCD-aware swizzle (grid %8==0 by construction), mb fastest (share B panel)
  const int nwg = gridDim.x;
  const int sw = ((int)blockIdx.x % 8) * (nwg / 8) + (int)blockIdx.x / 8;
  const int z = sw / (mB * nB);
  const int rem = sw % (mB * nB);
  const int rowBase = (rem % mB) * 256;
  const int colBase = (rem / mB) * 256;
  const int kBase = z * Ksub;
  const int nt = Ksub / 64;

  const int wv = threadIdx.x >> 6;
  const int lane = threadIdx.x & 63;
  const int wr = wv >> 2;  // 0..1 : A half (row block of 128)
  const int wc = wv & 3;   // 0..3 : 64-col block
  const int l16 = lane & 15;
  const int lk = lane >> 4;  // 0..3
  const int xl = l16 & 7;

  // ds_read bases (byte offsets into smem); +b*32768 per buffer, +m*2048/n*2048
  const int aBase0 = wr * 16384 + l16 * 128;
  const int bBase0 = 65536 + (wc >> 1) * 16384 + ((wc & 1) * 64 + l16) * 128;
  const int c0 = ((lk ^ xl)) * 16;        // ks=0 swizzled chunk byte
  const int c1 = (((4 + lk) ^ xl)) * 16;  // ks=1

  // staging source (pre-swizzled global so linear LDS dest holds swizzled data)
  const int srow = wv * 8 + (lane >> 3);            // 0..63 within issue block
  const int scol = ((lane & 7) ^ (lane >> 3)) * 8;  // bf16 elements
  const __hip_bfloat16* gA = A + (size_t)(rowBase + srow) * K + kBase + scol;
  const __hip_bfloat16* gB = Bt + (size_t)(colBase + srow) * K + kBase + scol;

  auto STAGE = [&](int kt, int bo) {
#pragma unroll
    for (int h = 0; h < 2; ++h)
#pragma unroll
      for (int j = 0; j < 2; ++j) {
        const size_t roff = (size_t)(h * 128 + j * 64) * K + (size_t)kt * 64;
        const int doff = h * 16384 + j * 8192 + wv * 1024;
        gload_lds16(gA + roff, smem + bo + doff);
        gload_lds16(gB + roff, smem + 65536 + bo + doff);
      }
  };

  f32x4 acc[8][4];
#pragma unroll
  for (int m = 0; m < 8; ++m)
#pragma unroll
    for (int n = 0; n < 4; ++n) acc[m][n] = (f32x4){0.f, 0.f, 0.f, 0.f};

  // prologue: stage kt0 -> buf0, kt1 -> buf1; wait kt0 only (counted)
  STAGE(0, 0);
  STAGE(1, 32768);
  asm volatile("s_waitcnt vmcnt(8)" ::: "memory");
  BARRIER();

  for (int t = 0; t < nt; ++t) {
    const int bo = (t & 1) * 32768;
    bf16x8 bq[4][2];
#pragma unroll
    for (int p = 0; p < 4; ++p) {
      bf16x8 af[2][2];
#pragma unroll
      for (int mm = 0; mm < 2; ++mm) {
        af[mm][0] = *(const bf16x8*)(smem + bo + aBase0 + (2 * p + mm) * 2048 + c0);
        af[mm][1] = *(const bf16x8*)(smem + bo + aBase0 + (2 * p + mm) * 2048 + c1);
      }
      if (p == 0) {
#pragma unroll
        for (int n = 0; n < 4; ++n) {
          bq[n][0] = *(const bf16x8*)(smem + bo + bBase0 + n * 2048 + c0);
          bq[n][1] = *(const bf16x8*)(smem + bo + bBase0 + n * 2048 + c1);
        }
      }
      BARRIER();
      asm volatile("s_waitcnt lgkmcnt(0)" ::: "memory");
      __builtin_amdgcn_sched_barrier(0);
      __builtin_amdgcn_s_setprio(1);
#pragma unroll
      for (int mm = 0; mm < 2; ++mm)
#pragma unroll
        for (int n = 0; n < 4; ++n) {
          acc[2 * p + mm][n] = __builtin_amdgcn_mfma_f32_16x16x32_bf16(
              af[mm][0], bq[n][0], acc[2 * p + mm][n], 0, 0, 0);
          acc[2 * p + mm][n] = __builtin_amdgcn_mfma_f32_16x16x32_bf16(
              af[mm][1], bq[n][1], acc[2 * p + mm][n], 0, 0, 0);
        }
      __builtin_amdgcn_s_setprio(0);
      BARRIER();
    }
    // stage kt t+2 into the buffer just consumed; counted vmcnt (never 0
    // mid-loop): wait until only the 8 just-issued loads remain -> t+1 ready.
    if (t + 2 < nt) {
      STAGE(t + 2, bo);
      asm volatile("s_waitcnt vmcnt(8)" ::: "memory");
      BARRIER();
    } else if (t + 2 == nt) {
      asm volatile("s_waitcnt vmcnt(0)" ::: "memory");
      BARRIER();
    }
  }

  __hip_bfloat16* Cz = C + (size_t)z * M * N;
  // C/D layout: col=lane&15, row=(lane>>4)*4+reg (verified m89)
#pragma unroll
  for (int m = 0; m < 8; ++m) {
#pragma unroll
    for (int n = 0; n < 4; ++n) {
#pragma unroll
      for (int j = 0; j < 4; ++j) {
        const int r = rowBase + wr * 128 + m * 16 + lk * 4 + j;
        const int c = colBase + wc * 64 + n * 16 + l16;
        float v = acc[m][n][j];
        if (EPI == 2) v = fmaxf(v + bias[c], 0.f);
        Cz[(size_t)r * N + c] = __float2bfloat16(v);
      }
    }
  }
}

// Fused: y = P0 + P1 + resid + bias;  out = (y - mean(y)) / sqrt(var(y))
// One wave per row (D=768 -> 12 elems/lane), 4 rows per block.
template <bool FINAL>
__global__ __launch_bounds__(256) void ln_fuse2(
    const __hip_bfloat16* __restrict__ P0, const __hip_bfloat16* __restrict__ P1,
    const float* __restrict__ residf, const __hip_bfloat16* __restrict__ residb,
    const float* __restrict__ bias, __hip_bfloat16* __restrict__ outb,
    float* __restrict__ outf) {
  const int wave = threadIdx.x >> 6, lane = threadIdx.x & 63;
  const size_t base = ((size_t)blockIdx.x * 4 + wave) * 768;

  float v[12];
  float s = 0.f, q = 0.f;
#pragma unroll
  for (int c = 0; c < 3; ++c) {
    const int col = c * 256 + lane * 4;
    ushort4 a = *reinterpret_cast<const ushort4*>(&P0[base + col]);
    ushort4 b = *reinterpret_cast<const ushort4*>(&P1[base + col]);
    float4 bs = *reinterpret_cast<const float4*>(&bias[col]);
    float r0, r1, r2, r3;
    if (FINAL) {
      ushort4 rb = *reinterpret_cast<const ushort4*>(&residb[base + col]);
      r0 = bf2f(rb.x); r1 = bf2f(rb.y); r2 = bf2f(rb.z); r3 = bf2f(rb.w);
    } else {
      float4 rf = *reinterpret_cast<const float4*>(&residf[base + col]);
      r0 = rf.x; r1 = rf.y; r2 = rf.z; r3 = rf.w;
    }
    float y0 = bf2f(a.x) + bf2f(b.x) + r0 + bs.x;
    float y1 = bf2f(a.y) + bf2f(b.y) + r1 + bs.y;
    float y2 = bf2f(a.z) + bf2f(b.z) + r2 + bs.z;
    float y3 = bf2f(a.w) + bf2f(b.w) + r3 + bs.w;
    v[c * 4 + 0] = y0; v[c * 4 + 1] = y1; v[c * 4 + 2] = y2; v[c * 4 + 3] = y3;
    s += y0 + y1 + y2 + y3;
    q += y0 * y0 + y1 * y1 + y2 * y2 + y3 * y3;
  }
#pragma unroll
  for (int off = 32; off; off >>= 1) {
    s += __shfl_xor(s, off);
    q += __shfl_xor(q, off);
  }
  const float mu = s * (1.f / 768.f);
  const float rs = rsqrtf(q * (1.f / 768.f) - mu * mu);
#pragma unroll
  for (int c = 0; c < 3; ++c) {
    const int col = c * 256 + lane * 4;
    if (FINAL) {
      float4 o;
      o.x = (v[c * 4 + 0] - mu) * rs;
      o.y = (v[c * 4 + 1] - mu) * rs;
      o.z = (v[c * 4 + 2] - mu) * rs;
      o.w = (v[c * 4 + 3] - mu) * rs;
      *reinterpret_cast<float4*>(&outf[base + col]) = o;
    } else {
      __hip_bfloat16 h0 = __float2bfloat16((v[c * 4 + 0] - mu) * rs);
      __hip_bfloat16 h1 = __float2bfloat16((v[c * 4 + 1] - mu) * rs);
      __hip_bfloat16 h2 = __float2bfloat16((v[c * 4 + 2] - mu) * rs);
      __hip_bfloat16 h3 = __float2bfloat16((v[c * 4 + 3] - mu) * rs);
      ushort4 o;
      o.x = *reinterpret_cast<unsigned short*>(&h0);
      o.y = *reinterpret_cast<unsigned short*>(&h1);
      o.z = *reinterpret_cast<unsigned short*>(&h2);
      o.w = *reinterpret_cast<unsigned short*>(&h3);
      *reinterpret_cast<ushort4*>(&outb[base + col]) = o;
    }
  }
}

// fp32 -> bf16 cast, 4 elements/thread
__global__ __launch_bounds__(256) void cast_bf16_kernel(
    const float* __restrict__ in, __hip_bfloat16* __restrict__ out, int n4) {
  int i = blockIdx.x * blockDim.x + threadIdx.x;
  if (i >= n4) return;
  float4 v = reinterpret_cast<const float4*>(in)[i];
  __hip_bfloat16 h0 = __float2bfloat16(v.x), h1 = __float2bfloat16(v.y);
  __hip_bfloat16 h2 = __float2bfloat16(v.z), h3 = __float2bfloat16(v.w);
  ushort4 o;
  o.x = *reinterpret_cast<unsigned short*>(&h0);
  o.y = *reinterpret_cast<unsigned short*>(&h1);
  o.z = *reinterpret_cast<unsigned short*>(&h2);
  o.w = *reinterpret_cast<unsigned short*>(&h3);
  reinterpret_cast<ushort4*>(out)[i] = o;
}

// W (KxN fp32) -> Wt (NxK bf16)
__global__ __launch_bounds__(256) void transpose_cast(
    const float* __restrict__ W, __hip_bfloat16* __restrict__ Wt, int K, int N) {
  __shared__ float tile[32][33];
  const int t = threadIdx.x;
  const int tx = t & 31;
  const int ty = t >> 5; // 0..7
  const int n0 = blockIdx.x * 32;
  const int k0 = blockIdx.y * 32;
#pragma unroll
  for (int i = 0; i < 32; i += 8)
    tile[ty + i][tx] = W[(size_t)(k0 + ty + i) * N + n0 + tx];
  __syncthreads();
#pragma unroll
  for (int i = 0; i < 32; i += 8)
    Wt[(size_t)(n0 + ty + i) * K + k0 + tx] = __float2bfloat16(tile[tx][ty + i]);
}

extern "C" void kernel_launch(void* const* d_in, const int* in_sizes, int n_in,
                              void* d_out, int out_size, void* d_ws,
                              size_t ws_size, hipStream_t stream) {
  const float* X = (const float*)d_in[0];
  const float* Wv = (const float*)d_in[5];
  const float* bv = (const float*)d_in[6];
  const float* W1 = (const float*)d_in[7];
  const float* b1 = (const float*)d_in[8];
  const float* W2 = (const float*)d_in[9];
  const float* b2 = (const float*)d_in[10];
  float* out = (float*)d_out;

  const int M = 4 * 2048; // 8192 rows
  const int D = 768, H = 3072;

  // workspace layout (bytes), total 92,798,976:
  //  [0, 25165824)        : P3 (2 bf16 partials of GEMM3) -- overlaps Xb/Wvt/W1t
  //    [0, 12582912)      : Xb           (dead after GEMM1)
  //    [12582912, ...)    : Wvt 1179648  (dead after GEMM1)
  //    [13762560, ...)    : W1t 4718592  (dead after GEMM2)
  //  [25165824, 29884416) : W2t
  //  [29884416, 42467328) : X1b
  //  [42467328, 92798976) : Gb (8192x3072 bf16)
  //    [42467328, 67633152): P1 (2 bf16 partials of GEMM1, dead before GEMM2)
  char* ws = (char*)d_ws;
  __hip_bfloat16* P3 = (__hip_bfloat16*)(ws);
  __hip_bfloat16* Xb = (__hip_bfloat16*)(ws);
  __hip_bfloat16* Wvt = (__hip_bfloat16*)(ws + 12582912);
  __hip_bfloat16* W1t = (__hip_bfloat16*)(ws + 13762560);
  __hip_bfloat16* W2t = (__hip_bfloat16*)(ws + 25165824);
  __hip_bfloat16* X1b = (__hip_bfloat16*)(ws + 29884416);
  __hip_bfloat16* Gb = (__hip_bfloat16*)(ws + 42467328);
  __hip_bfloat16* P1 = (__hip_bfloat16*)(ws + 42467328);

  cast_bf16_kernel<<<dim3((M * D / 4 + 255) / 256), 256, 0, stream>>>(X, Xb,
                                                                      M * D / 4);
  transpose_cast<<<dim3(D / 32, D / 32), 256, 0, stream>>>(Wv, Wvt, D, D);
  transpose_cast<<<dim3(H / 32, D / 32), 256, 0, stream>>>(W1, W1t, D, H);
  transpose_cast<<<dim3(D / 32, H / 32), 256, 0, stream>>>(W2, W2t, H, D);

  // GEMM1 split-K x2: P1[z] = Xb @ Wvt (z-th K half); grid 32*3*2 = 192
  gemm256<0><<<192, 512, 0, stream>>>(Xb, Wvt, P1, nullptr, M, D, D, D / 2, 32, 3);
  // X1 = LN(P1_0 + P1_1 + X + bv)
  ln_fuse2<false><<<M / 4, 256, 0, stream>>>(P1, P1 + (size_t)M * D, X, nullptr,
                                             bv, X1b, nullptr);
  // G = relu(X1@W1 + b1); grid 32*12 = 384
  gemm256<2><<<384, 512, 0, stream>>>(X1b, W1t, Gb, b1, M, H, D, D, 32, 12);
  // GEMM3 split-K x2: P3[z] = Gb @ W2t; grid 32*3*2 = 192
  gemm256<0><<<192, 512, 0, stream>>>(Gb, W2t, P3, nullptr, M, D, H, H / 2, 32, 3);
  // out = LN(P3_0 + P3_1 + X1b + b2)
  ln_fuse2<true><<<M / 4, 256, 0, stream>>>(P3, P3 + (size_t)M * D, nullptr,
                                            X1b, b2, nullptr, out);
}

// Round 4
// 130.058 us; speedup vs baseline: 1.3423x; 1.3423x over previous
//
#include <hip/hip_runtime.h>
#include <hip/hip_bf16.h>
#include <math.h>

// ---------------------------------------------------------------------------
// Math note: softmax(A, axis=2) then sum(A, axis=2, keepdims=True) * V == V.
// Pipeline: X1 = LN(X + X@Wv + bv); out = LN(X1 + relu(X1@W1+b1)@W2 + b2)
//
// Round-4: 128xBN tiles (BN=128 or 96), BK=64, 4 waves, 2 blocks/CU (TLP),
// double-buffered LDS with counted-vmcnt 2-deep prefetch, raw s_barrier,
// zero-conflict XOR swizzle (both-sides involution), residuals fused into
// GEMM epilogues (no split-K partials anywhere).
//  - GEMM1 (8192x 768x 768, BN=96): grid 512  = 1 exact resident round
//  - GEMM2 (8192x3072x 768, BN=128): grid 1536 = 3 exact rounds
//  - GEMM3 (8192x 768x3072, BN=96): grid 512, nt=48 deep pipeline
// ---------------------------------------------------------------------------

typedef __bf16 bf16x8 __attribute__((ext_vector_type(8)));
typedef float f32x4 __attribute__((ext_vector_type(4)));

__device__ inline void gload_lds16(const __hip_bfloat16* g, void* lds) {
  __builtin_amdgcn_global_load_lds(
      (const __attribute__((address_space(1))) void*)g,
      (__attribute__((address_space(3))) void*)lds, 16, 0, 0);
}

__device__ inline float bf2f(unsigned short u) {
  union { unsigned int i; float f; } x;
  x.i = ((unsigned int)u) << 16;
  return x.f;
}

#define BARRIER() asm volatile("s_barrier" ::: "memory")

// C(MxN) = A(MxK) @ Bt(NxK)^T, 128 x BNv tile, BK=64, 4 waves (2x2).
// EPI==1: +bias +fp32 residual -> bf16
// EPI==2: +bias, relu          -> bf16
// EPI==3: +bias +bf16 residual -> bf16
template <int BNv, int EPI>
__global__ __launch_bounds__(256, 2) void gemm128(
    const __hip_bfloat16* __restrict__ A, const __hip_bfloat16* __restrict__ Bt,
    __hip_bfloat16* __restrict__ C, const float* __restrict__ bias,
    const float* __restrict__ residf, const __hip_bfloat16* __restrict__ residb,
    int M, int N, int K) {
  constexpr int NF = BNv / 32;   // n-frags per wave (4 or 3)
  constexpr int BI = BNv / 32;   // B stage instrs per wave
  constexpr int BS = BNv * 128;  // bytes per B buffer
  constexpr int S = 4 + BI;      // stage loads per wave per K-tile
  // smem: A0[16K] A1[16K] B0[BS] B1[BS]
  __shared__ __align__(16) char smem[32768 + 2 * BS];

  const int bid = blockIdx.x;
  const int mB = M / 128;
  const int rowBase = (bid % mB) * 128;  // row-fastest: XCD round-robin keeps
  const int colBase = (bid / mB) * BNv;  // all XCDs on the same A rows (L3)
  const int nt = K / 64;

  const int wv = threadIdx.x >> 6;
  const int lane = threadIdx.x & 63;
  const int wr = wv >> 1, wc = wv & 1;   // 2x2 waves
  const int l16 = lane & 15, lk = lane >> 4;

  // ---- staging (pre-swizzled global source, linear LDS dest; rule 21) ----
  const int rA = lane >> 3;               // 0..7 row within 8-row stripe
  const int cSw = ((lane & 7) ^ rA) * 8;  // logical col = phys ^ (row&7)
  const __hip_bfloat16* gA = A + (size_t)(rowBase + wv * 32 + rA) * K + cSw;
  const __hip_bfloat16* gB =
      Bt + (size_t)(colBase + wv * 8 * BI + rA) * K + cSw;

  auto STAGE = [&](int kt, int b) {
    const size_t ko = (size_t)kt * 64;
#pragma unroll
    for (int i = 0; i < 4; ++i)
      gload_lds16(gA + (size_t)i * 8 * K + ko,
                  smem + b * 16384 + (wv * 4 + i) * 1024);
#pragma unroll
    for (int i = 0; i < BI; ++i)
      gload_lds16(gB + (size_t)i * 8 * K + ko,
                  smem + 32768 + b * BS + (wv * BI + i) * 1024);
  };

  // ---- ds_read addressing (swizzled chunk: phys = logical ^ (row&7)) ----
  const int aBase = (wr * 64 + l16) * 128;          // + m*2048 + cph[ks]
  const int bBase = (wc * (BNv / 2) + l16) * 128;   // + n*2048 + cph[ks]
  const int xr = l16 & 7;
  const int cph0 = ((lk) ^ xr) * 16;
  const int cph1 = ((4 + lk) ^ xr) * 16;

  f32x4 acc[4][NF];
#pragma unroll
  for (int m = 0; m < 4; ++m)
#pragma unroll
    for (int n = 0; n < NF; ++n) acc[m][n] = (f32x4){0.f, 0.f, 0.f, 0.f};

  STAGE(0, 0);
  if (nt > 1) {
    STAGE(1, 1);
    if constexpr (BNv == 128)
      asm volatile("s_waitcnt vmcnt(8)" ::: "memory");
    else
      asm volatile("s_waitcnt vmcnt(7)" ::: "memory");
  } else {
    asm volatile("s_waitcnt vmcnt(0)" ::: "memory");
  }
  BARRIER();

  for (int t = 0; t < nt; ++t) {
    const int b = t & 1;
    const char* pa = smem + b * 16384 + aBase;
    const char* pb = smem + 32768 + b * BS + bBase;

    bf16x8 af0[4], af1[4], bf0[NF], bf1[NF];
#pragma unroll
    for (int m = 0; m < 4; ++m) af0[m] = *(const bf16x8*)(pa + m * 2048 + cph0);
#pragma unroll
    for (int n = 0; n < NF; ++n) bf0[n] = *(const bf16x8*)(pb + n * 2048 + cph0);
#pragma unroll
    for (int m = 0; m < 4; ++m) af1[m] = *(const bf16x8*)(pa + m * 2048 + cph1);
#pragma unroll
    for (int n = 0; n < NF; ++n) bf1[n] = *(const bf16x8*)(pb + n * 2048 + cph1);

    // wait for ks=0 frags only (in-order DS returns): outstanding <= 4+NF
    if constexpr (NF == 4)
      asm volatile("s_waitcnt lgkmcnt(8)" ::: "memory");
    else
      asm volatile("s_waitcnt lgkmcnt(7)" ::: "memory");
    __builtin_amdgcn_sched_barrier(0);
    __builtin_amdgcn_s_setprio(1);
#pragma unroll
    for (int m = 0; m < 4; ++m)
#pragma unroll
      for (int n = 0; n < NF; ++n)
        acc[m][n] = __builtin_amdgcn_mfma_f32_16x16x32_bf16(af0[m], bf0[n],
                                                            acc[m][n], 0, 0, 0);
    __builtin_amdgcn_s_setprio(0);
    asm volatile("s_waitcnt lgkmcnt(0)" ::: "memory");
    __builtin_amdgcn_sched_barrier(0);
    __builtin_amdgcn_s_setprio(1);
#pragma unroll
    for (int m = 0; m < 4; ++m)
#pragma unroll
      for (int n = 0; n < NF; ++n)
        acc[m][n] = __builtin_amdgcn_mfma_f32_16x16x32_bf16(af1[m], bf1[n],
                                                            acc[m][n], 0, 0, 0);
    __builtin_amdgcn_s_setprio(0);

    BARRIER();  // all waves done reading buffer b
    if (t + 2 < nt) {
      STAGE(t + 2, b);  // overwrite just-consumed buffer
      // counted: wait until only the S just-issued remain -> t+1 ready
      if constexpr (BNv == 128)
        asm volatile("s_waitcnt vmcnt(8)" ::: "memory");
      else
        asm volatile("s_waitcnt vmcnt(7)" ::: "memory");
      BARRIER();
    } else if (t + 2 == nt) {
      asm volatile("s_waitcnt vmcnt(0)" ::: "memory");
      BARRIER();
    }
  }

  // epilogue: C/D layout col=lane&15, row=(lane>>4)*4+reg (verified m89)
#pragma unroll
  for (int m = 0; m < 4; ++m) {
#pragma unroll
    for (int n = 0; n < NF; ++n) {
#pragma unroll
      for (int j = 0; j < 4; ++j) {
        const int r = rowBase + wr * 64 + m * 16 + lk * 4 + j;
        const int c = colBase + wc * (BNv / 2) + n * 16 + l16;
        const size_t idx = (size_t)r * N + c;
        float v = acc[m][n][j] + bias[c];
        if (EPI == 1) v += residf[idx];
        if (EPI == 2) v = fmaxf(v, 0.f);
        if (EPI == 3) v += __bfloat162float(residb[idx]);
        C[idx] = __float2bfloat16(v);
      }
    }
  }
}

// LayerNorm over D=768 (biased variance, no eps): one wave per row.
template <bool OUTF>
__global__ __launch_bounds__(256) void ln_simple(
    const __hip_bfloat16* __restrict__ Y, __hip_bfloat16* __restrict__ outb,
    float* __restrict__ outf) {
  const int wave = threadIdx.x >> 6, lane = threadIdx.x & 63;
  const size_t base = ((size_t)blockIdx.x * 4 + wave) * 768;

  float v[12];
  float s = 0.f, q = 0.f;
#pragma unroll
  for (int c = 0; c < 3; ++c) {
    const int col = c * 256 + lane * 4;
    ushort4 a = *reinterpret_cast<const ushort4*>(&Y[base + col]);
    float y0 = bf2f(a.x), y1 = bf2f(a.y), y2 = bf2f(a.z), y3 = bf2f(a.w);
    v[c * 4 + 0] = y0; v[c * 4 + 1] = y1; v[c * 4 + 2] = y2; v[c * 4 + 3] = y3;
    s += y0 + y1 + y2 + y3;
    q += y0 * y0 + y1 * y1 + y2 * y2 + y3 * y3;
  }
#pragma unroll
  for (int off = 32; off; off >>= 1) {
    s += __shfl_xor(s, off);
    q += __shfl_xor(q, off);
  }
  const float mu = s * (1.f / 768.f);
  const float rs = rsqrtf(q * (1.f / 768.f) - mu * mu);
#pragma unroll
  for (int c = 0; c < 3; ++c) {
    const int col = c * 256 + lane * 4;
    if (OUTF) {
      float4 o;
      o.x = (v[c * 4 + 0] - mu) * rs;
      o.y = (v[c * 4 + 1] - mu) * rs;
      o.z = (v[c * 4 + 2] - mu) * rs;
      o.w = (v[c * 4 + 3] - mu) * rs;
      *reinterpret_cast<float4*>(&outf[base + col]) = o;
    } else {
      __hip_bfloat16 h0 = __float2bfloat16((v[c * 4 + 0] - mu) * rs);
      __hip_bfloat16 h1 = __float2bfloat16((v[c * 4 + 1] - mu) * rs);
      __hip_bfloat16 h2 = __float2bfloat16((v[c * 4 + 2] - mu) * rs);
      __hip_bfloat16 h3 = __float2bfloat16((v[c * 4 + 3] - mu) * rs);
      ushort4 o;
      o.x = *reinterpret_cast<unsigned short*>(&h0);
      o.y = *reinterpret_cast<unsigned short*>(&h1);
      o.z = *reinterpret_cast<unsigned short*>(&h2);
      o.w = *reinterpret_cast<unsigned short*>(&h3);
      *reinterpret_cast<ushort4*>(&outb[base + col]) = o;
    }
  }
}

// fp32 -> bf16 cast, 4 elements/thread
__global__ __launch_bounds__(256) void cast_bf16_kernel(
    const float* __restrict__ in, __hip_bfloat16* __restrict__ out, int n4) {
  int i = blockIdx.x * blockDim.x + threadIdx.x;
  if (i >= n4) return;
  float4 v = reinterpret_cast<const float4*>(in)[i];
  __hip_bfloat16 h0 = __float2bfloat16(v.x), h1 = __float2bfloat16(v.y);
  __hip_bfloat16 h2 = __float2bfloat16(v.z), h3 = __float2bfloat16(v.w);
  ushort4 o;
  o.x = *reinterpret_cast<unsigned short*>(&h0);
  o.y = *reinterpret_cast<unsigned short*>(&h1);
  o.z = *reinterpret_cast<unsigned short*>(&h2);
  o.w = *reinterpret_cast<unsigned short*>(&h3);
  reinterpret_cast<ushort4*>(out)[i] = o;
}

// W (KxN fp32) -> Wt (NxK bf16)
__global__ __launch_bounds__(256) void transpose_cast(
    const float* __restrict__ W, __hip_bfloat16* __restrict__ Wt, int K, int N) {
  __shared__ float tile[32][33];
  const int t = threadIdx.x;
  const int tx = t & 31;
  const int ty = t >> 5; // 0..7
  const int n0 = blockIdx.x * 32;
  const int k0 = blockIdx.y * 32;
#pragma unroll
  for (int i = 0; i < 32; i += 8)
    tile[ty + i][tx] = W[(size_t)(k0 + ty + i) * N + n0 + tx];
  __syncthreads();
#pragma unroll
  for (int i = 0; i < 32; i += 8)
    Wt[(size_t)(n0 + ty + i) * K + k0 + tx] = __float2bfloat16(tile[tx][ty + i]);
}

extern "C" void kernel_launch(void* const* d_in, const int* in_sizes, int n_in,
                              void* d_out, int out_size, void* d_ws,
                              size_t ws_size, hipStream_t stream) {
  const float* X = (const float*)d_in[0];
  const float* Wv = (const float*)d_in[5];
  const float* bv = (const float*)d_in[6];
  const float* W1 = (const float*)d_in[7];
  const float* b1 = (const float*)d_in[8];
  const float* W2 = (const float*)d_in[9];
  const float* b2 = (const float*)d_in[10];
  float* out = (float*)d_out;

  const int M = 4 * 2048; // 8192 rows
  const int D = 768, H = 3072;

  // workspace layout (bytes), total 98,697,216:
  //  Xb   @ 0         (12,582,912)
  //  Wvt  @ 12582912  ( 1,179,648)
  //  W1t  @ 13762560  ( 4,718,592)
  //  W2t  @ 18481152  ( 4,718,592)
  //  Yb   @ 23199744  (12,582,912)   (reused as Y2b after LN1)
  //  X1b  @ 35782656  (12,582,912)
  //  Gb   @ 48365568  (50,331,648)
  char* ws = (char*)d_ws;
  __hip_bfloat16* Xb  = (__hip_bfloat16*)(ws);
  __hip_bfloat16* Wvt = (__hip_bfloat16*)(ws + 12582912);
  __hip_bfloat16* W1t = (__hip_bfloat16*)(ws + 13762560);
  __hip_bfloat16* W2t = (__hip_bfloat16*)(ws + 18481152);
  __hip_bfloat16* Yb  = (__hip_bfloat16*)(ws + 23199744);
  __hip_bfloat16* X1b = (__hip_bfloat16*)(ws + 35782656);
  __hip_bfloat16* Gb  = (__hip_bfloat16*)(ws + 48365568);
  __hip_bfloat16* Y2b = Yb;  // Yb dead after LN1

  cast_bf16_kernel<<<dim3((M * D / 4 + 255) / 256), 256, 0, stream>>>(X, Xb,
                                                                      M * D / 4);
  transpose_cast<<<dim3(D / 32, D / 32), 256, 0, stream>>>(Wv, Wvt, D, D);
  transpose_cast<<<dim3(H / 32, D / 32), 256, 0, stream>>>(W1, W1t, D, H);
  transpose_cast<<<dim3(D / 32, H / 32), 256, 0, stream>>>(W2, W2t, H, D);

  // Y = X@Wv + bv + X  (fused residual), grid 64*8 = 512
  gemm128<96, 1><<<512, 256, 0, stream>>>(Xb, Wvt, Yb, bv, X, nullptr, M, D, D);
  // X1 = LN(Y)
  ln_simple<false><<<M / 4, 256, 0, stream>>>(Yb, X1b, nullptr);
  // G = relu(X1@W1 + b1), grid 64*24 = 1536
  gemm128<128, 2><<<1536, 256, 0, stream>>>(X1b, W1t, Gb, b1, nullptr, nullptr,
                                            M, H, D);
  // Y2 = G@W2 + b2 + X1 (fused residual), grid 64*8 = 512, nt = 48
  gemm128<96, 3><<<512, 256, 0, stream>>>(Gb, W2t, Y2b, b2, nullptr, X1b, M, D,
                                          H);
  // out = LN(Y2)
  ln_simple<true><<<M / 4, 256, 0, stream>>>(Y2b, nullptr, out);
}

// Round 5
// 125.268 us; speedup vs baseline: 1.3936x; 1.0382x over previous
//
#include <hip/hip_runtime.h>
#include <hip/hip_bf16.h>
#include <math.h>

// ---------------------------------------------------------------------------
// Math note: softmax(A, axis=2) then sum(A, axis=2, keepdims=True) * V == V.
// Pipeline: X1 = LN(X + X@Wv + bv); out = LN(X1 + relu(X1@W1+b1)@W2 + b2)
//
// Round-5: same tiles/grids as round-4 (128xBN, BK=64, 4 waves, 2 blocks/CU)
// but restructured K-loop: STAGE issued under ks1 MFMAs (T14 issue-early),
// ks0 MFMAs hide ks1 ds_read latency, counted vmcnt after compute.
//  - GEMM1 (8192x 768x 768, BN=96): grid 512  = 1 exact resident round
//  - GEMM2 (8192x3072x 768, BN=128): grid 1536 = 3 exact rounds
//  - GEMM3 (8192x 768x3072, BN=96): grid 512, nt=48 deep pipeline
// Pre-processing (fp32->bf16 cast + 3 weight transposes) merged into 1 launch.
// ---------------------------------------------------------------------------

typedef __bf16 bf16x8 __attribute__((ext_vector_type(8)));
typedef float f32x4 __attribute__((ext_vector_type(4)));

__device__ inline void gload_lds16(const __hip_bfloat16* g, void* lds) {
  __builtin_amdgcn_global_load_lds(
      (const __attribute__((address_space(1))) void*)g,
      (__attribute__((address_space(3))) void*)lds, 16, 0, 0);
}

__device__ inline float bf2f(unsigned short u) {
  union { unsigned int i; float f; } x;
  x.i = ((unsigned int)u) << 16;
  return x.f;
}

#define BARRIER() asm volatile("s_barrier" ::: "memory")

// C(MxN) = A(MxK) @ Bt(NxK)^T, 128 x BNv tile, BK=64, 4 waves (2x2).
// EPI==1: +bias +fp32 residual -> bf16
// EPI==2: +bias, relu          -> bf16
// EPI==3: +bias +bf16 residual -> bf16
template <int BNv, int EPI>
__global__ __launch_bounds__(256, 2) void gemm128(
    const __hip_bfloat16* __restrict__ A, const __hip_bfloat16* __restrict__ Bt,
    __hip_bfloat16* __restrict__ C, const float* __restrict__ bias,
    const float* __restrict__ residf, const __hip_bfloat16* __restrict__ residb,
    int M, int N, int K) {
  constexpr int NF = BNv / 32;   // n-frags per wave (4 or 3)
  constexpr int BI = BNv / 32;   // B stage instrs per wave
  constexpr int BS = BNv * 128;  // bytes per B buffer
  // smem: A0[16K] A1[16K] B0[BS] B1[BS]
  __shared__ __align__(16) char smem[32768 + 2 * BS];

  const int bid = blockIdx.x;
  const int mB = M / 128;
  const int rowBase = (bid % mB) * 128;  // row-fastest: XCD round-robin keeps
  const int colBase = (bid / mB) * BNv;  // all XCDs on the same A rows (L3)
  const int nt = K / 64;

  const int wv = threadIdx.x >> 6;
  const int lane = threadIdx.x & 63;
  const int wr = wv >> 1, wc = wv & 1;   // 2x2 waves
  const int l16 = lane & 15, lk = lane >> 4;

  // ---- staging (pre-swizzled global source, linear LDS dest; rule 21) ----
  const int rA = lane >> 3;               // 0..7 row within 8-row stripe
  const int cSw = ((lane & 7) ^ rA) * 8;  // logical col = phys ^ (row&7)
  const __hip_bfloat16* gA = A + (size_t)(rowBase + wv * 32 + rA) * K + cSw;
  const __hip_bfloat16* gB =
      Bt + (size_t)(colBase + wv * 8 * BI + rA) * K + cSw;

  auto STAGE = [&](int kt, int b) {
    const size_t ko = (size_t)kt * 64;
#pragma unroll
    for (int i = 0; i < 4; ++i)
      gload_lds16(gA + (size_t)i * 8 * K + ko,
                  smem + b * 16384 + (wv * 4 + i) * 1024);
#pragma unroll
    for (int i = 0; i < BI; ++i)
      gload_lds16(gB + (size_t)i * 8 * K + ko,
                  smem + 32768 + b * BS + (wv * BI + i) * 1024);
  };

  // ---- ds_read addressing (swizzled chunk: phys = logical ^ (row&7)) ----
  const int aBase = (wr * 64 + l16) * 128;          // + m*2048 + cph[ks]
  const int bBase = (wc * (BNv / 2) + l16) * 128;   // + n*2048 + cph[ks]
  const int xr = l16 & 7;
  const int cph0 = ((lk) ^ xr) * 16;
  const int cph1 = ((4 + lk) ^ xr) * 16;

  f32x4 acc[4][NF];
#pragma unroll
  for (int m = 0; m < 4; ++m)
#pragma unroll
    for (int n = 0; n < NF; ++n) acc[m][n] = (f32x4){0.f, 0.f, 0.f, 0.f};

  STAGE(0, 0);
  if (nt > 1) {
    STAGE(1, 1);
    if constexpr (BNv == 128)
      asm volatile("s_waitcnt vmcnt(8)" ::: "memory");
    else
      asm volatile("s_waitcnt vmcnt(7)" ::: "memory");
  } else {
    asm volatile("s_waitcnt vmcnt(0)" ::: "memory");
  }
  BARRIER();

  for (int t = 0; t < nt; ++t) {
    const int b = t & 1;
    const char* pa = smem + b * 16384 + aBase;
    const char* pb = smem + 32768 + b * BS + bBase;

    bf16x8 af0[4], af1[4], bf0[NF], bf1[NF];
#pragma unroll
    for (int m = 0; m < 4; ++m) af0[m] = *(const bf16x8*)(pa + m * 2048 + cph0);
#pragma unroll
    for (int n = 0; n < NF; ++n) bf0[n] = *(const bf16x8*)(pb + n * 2048 + cph0);
#pragma unroll
    for (int m = 0; m < 4; ++m) af1[m] = *(const bf16x8*)(pa + m * 2048 + cph1);
#pragma unroll
    for (int n = 0; n < NF; ++n) bf1[n] = *(const bf16x8*)(pb + n * 2048 + cph1);

    // ks0 frags ready when only the (4+NF) ks1 reads remain (in-order DS)
    if constexpr (NF == 4)
      asm volatile("s_waitcnt lgkmcnt(8)" ::: "memory");
    else
      asm volatile("s_waitcnt lgkmcnt(7)" ::: "memory");
    __builtin_amdgcn_sched_barrier(0);
    __builtin_amdgcn_s_setprio(1);
#pragma unroll
    for (int m = 0; m < 4; ++m)
#pragma unroll
      for (int n = 0; n < NF; ++n)
        acc[m][n] = __builtin_amdgcn_mfma_f32_16x16x32_bf16(af0[m], bf0[n],
                                                            acc[m][n], 0, 0, 0);
    __builtin_amdgcn_s_setprio(0);
    asm volatile("s_waitcnt lgkmcnt(0)" ::: "memory");
    __builtin_amdgcn_sched_barrier(0);
    BARRIER();  // all waves' reads of buffer b complete -> safe to overwrite

    if (t + 2 < nt) STAGE(t + 2, b);  // async issue; overlaps ks1 MFMAs

    __builtin_amdgcn_s_setprio(1);
#pragma unroll
    for (int m = 0; m < 4; ++m)
#pragma unroll
      for (int n = 0; n < NF; ++n)
        acc[m][n] = __builtin_amdgcn_mfma_f32_16x16x32_bf16(af1[m], bf1[n],
                                                            acc[m][n], 0, 0, 0);
    __builtin_amdgcn_s_setprio(0);

    if (t + 1 < nt) {
      // tile t+1's loads must have landed (mine via vmcnt, others via barrier)
      if (t + 2 < nt) {
        if constexpr (BNv == 128)
          asm volatile("s_waitcnt vmcnt(8)" ::: "memory");
        else
          asm volatile("s_waitcnt vmcnt(7)" ::: "memory");
      } else {
        asm volatile("s_waitcnt vmcnt(0)" ::: "memory");
      }
      BARRIER();
    }
  }

  // epilogue: C/D layout col=lane&15, row=(lane>>4)*4+reg (verified m89)
#pragma unroll
  for (int m = 0; m < 4; ++m) {
#pragma unroll
    for (int n = 0; n < NF; ++n) {
#pragma unroll
      for (int j = 0; j < 4; ++j) {
        const int r = rowBase + wr * 64 + m * 16 + lk * 4 + j;
        const int c = colBase + wc * (BNv / 2) + n * 16 + l16;
        const size_t idx = (size_t)r * N + c;
        float v = acc[m][n][j] + bias[c];
        if (EPI == 1) v += residf[idx];
        if (EPI == 2) v = fmaxf(v, 0.f);
        if (EPI == 3) v += __bfloat162float(residb[idx]);
        C[idx] = __float2bfloat16(v);
      }
    }
  }
}

// LayerNorm over D=768 (biased variance, no eps): one wave per row.
template <bool OUTF>
__global__ __launch_bounds__(256) void ln_simple(
    const __hip_bfloat16* __restrict__ Y, __hip_bfloat16* __restrict__ outb,
    float* __restrict__ outf) {
  const int wave = threadIdx.x >> 6, lane = threadIdx.x & 63;
  const size_t base = ((size_t)blockIdx.x * 4 + wave) * 768;

  float v[12];
  float s = 0.f, q = 0.f;
#pragma unroll
  for (int c = 0; c < 3; ++c) {
    const int col = c * 256 + lane * 4;
    ushort4 a = *reinterpret_cast<const ushort4*>(&Y[base + col]);
    float y0 = bf2f(a.x), y1 = bf2f(a.y), y2 = bf2f(a.z), y3 = bf2f(a.w);
    v[c * 4 + 0] = y0; v[c * 4 + 1] = y1; v[c * 4 + 2] = y2; v[c * 4 + 3] = y3;
    s += y0 + y1 + y2 + y3;
    q += y0 * y0 + y1 * y1 + y2 * y2 + y3 * y3;
  }
#pragma unroll
  for (int off = 32; off; off >>= 1) {
    s += __shfl_xor(s, off);
    q += __shfl_xor(q, off);
  }
  const float mu = s * (1.f / 768.f);
  const float rs = rsqrtf(q * (1.f / 768.f) - mu * mu);
#pragma unroll
  for (int c = 0; c < 3; ++c) {
    const int col = c * 256 + lane * 4;
    if (OUTF) {
      float4 o;
      o.x = (v[c * 4 + 0] - mu) * rs;
      o.y = (v[c * 4 + 1] - mu) * rs;
      o.z = (v[c * 4 + 2] - mu) * rs;
      o.w = (v[c * 4 + 3] - mu) * rs;
      *reinterpret_cast<float4*>(&outf[base + col]) = o;
    } else {
      __hip_bfloat16 h0 = __float2bfloat16((v[c * 4 + 0] - mu) * rs);
      __hip_bfloat16 h1 = __float2bfloat16((v[c * 4 + 1] - mu) * rs);
      __hip_bfloat16 h2 = __float2bfloat16((v[c * 4 + 2] - mu) * rs);
      __hip_bfloat16 h3 = __float2bfloat16((v[c * 4 + 3] - mu) * rs);
      ushort4 o;
      o.x = *reinterpret_cast<unsigned short*>(&h0);
      o.y = *reinterpret_cast<unsigned short*>(&h1);
      o.z = *reinterpret_cast<unsigned short*>(&h2);
      o.w = *reinterpret_cast<unsigned short*>(&h3);
      *reinterpret_cast<ushort4*>(&outb[base + col]) = o;
    }
  }
}

// Transpose-cast tile helper: W (KxN fp32) -> Wt (NxK bf16), 32x32 tile.
__device__ inline void tc_tile(const float* __restrict__ W,
                               __hip_bfloat16* __restrict__ Wt, int K, int N,
                               int n0, int k0, int t) {
  __shared__ float tile[32][33];
  const int tx = t & 31;
  const int ty = t >> 5;  // 0..7
#pragma unroll
  for (int i = 0; i < 32; i += 8)
    tile[ty + i][tx] = W[(size_t)(k0 + ty + i) * N + n0 + tx];
  __syncthreads();
#pragma unroll
  for (int i = 0; i < 32; i += 8)
    Wt[(size_t)(n0 + ty + i) * K + k0 + tx] = __float2bfloat16(tile[tx][ty + i]);
}

// Merged preprocessing: X cast (blocks [0,6144)), Wv^T [6144,6720),
// W1^T [6720,9024), W2^T [9024,11328).
__global__ __launch_bounds__(256) void prep_kernel(
    const float* __restrict__ X, const float* __restrict__ Wv,
    const float* __restrict__ W1, const float* __restrict__ W2,
    __hip_bfloat16* __restrict__ Xb, __hip_bfloat16* __restrict__ Wvt,
    __hip_bfloat16* __restrict__ W1t, __hip_bfloat16* __restrict__ W2t) {
  const int bid = blockIdx.x;
  const int t = threadIdx.x;
  if (bid < 6144) {  // cast 8192*768 fp32 -> bf16, 4/thread
    const int i = bid * 256 + t;
    float4 v = reinterpret_cast<const float4*>(X)[i];
    __hip_bfloat16 h0 = __float2bfloat16(v.x), h1 = __float2bfloat16(v.y);
    __hip_bfloat16 h2 = __float2bfloat16(v.z), h3 = __float2bfloat16(v.w);
    ushort4 o;
    o.x = *reinterpret_cast<unsigned short*>(&h0);
    o.y = *reinterpret_cast<unsigned short*>(&h1);
    o.z = *reinterpret_cast<unsigned short*>(&h2);
    o.w = *reinterpret_cast<unsigned short*>(&h3);
    reinterpret_cast<ushort4*>(Xb)[i] = o;
  } else if (bid < 6720) {  // Wv (768x768)
    const int idx = bid - 6144;
    tc_tile(Wv, Wvt, 768, 768, (idx % 24) * 32, (idx / 24) * 32, t);
  } else if (bid < 9024) {  // W1 (768x3072) -> W1t (3072x768)
    const int idx = bid - 6720;
    tc_tile(W1, W1t, 768, 3072, (idx % 96) * 32, (idx / 96) * 32, t);
  } else {  // W2 (3072x768) -> W2t (768x3072)
    const int idx = bid - 9024;
    tc_tile(W2, W2t, 3072, 768, (idx % 24) * 32, (idx / 24) * 32, t);
  }
}

extern "C" void kernel_launch(void* const* d_in, const int* in_sizes, int n_in,
                              void* d_out, int out_size, void* d_ws,
                              size_t ws_size, hipStream_t stream) {
  const float* X = (const float*)d_in[0];
  const float* Wv = (const float*)d_in[5];
  const float* bv = (const float*)d_in[6];
  const float* W1 = (const float*)d_in[7];
  const float* b1 = (const float*)d_in[8];
  const float* W2 = (const float*)d_in[9];
  const float* b2 = (const float*)d_in[10];
  float* out = (float*)d_out;

  const int M = 4 * 2048; // 8192 rows
  const int D = 768, H = 3072;

  // workspace layout (bytes), total 98,697,216:
  //  Xb   @ 0         (12,582,912)
  //  Wvt  @ 12582912  ( 1,179,648)
  //  W1t  @ 13762560  ( 4,718,592)
  //  W2t  @ 18481152  ( 4,718,592)
  //  Yb   @ 23199744  (12,582,912)   (reused as Y2b after LN1)
  //  X1b  @ 35782656  (12,582,912)
  //  Gb   @ 48365568  (50,331,648)
  char* ws = (char*)d_ws;
  __hip_bfloat16* Xb  = (__hip_bfloat16*)(ws);
  __hip_bfloat16* Wvt = (__hip_bfloat16*)(ws + 12582912);
  __hip_bfloat16* W1t = (__hip_bfloat16*)(ws + 13762560);
  __hip_bfloat16* W2t = (__hip_bfloat16*)(ws + 18481152);
  __hip_bfloat16* Yb  = (__hip_bfloat16*)(ws + 23199744);
  __hip_bfloat16* X1b = (__hip_bfloat16*)(ws + 35782656);
  __hip_bfloat16* Gb  = (__hip_bfloat16*)(ws + 48365568);
  __hip_bfloat16* Y2b = Yb;  // Yb dead after LN1

  prep_kernel<<<11328, 256, 0, stream>>>(X, Wv, W1, W2, Xb, Wvt, W1t, W2t);

  // Y = X@Wv + bv + X  (fused residual), grid 64*8 = 512
  gemm128<96, 1><<<512, 256, 0, stream>>>(Xb, Wvt, Yb, bv, X, nullptr, M, D, D);
  // X1 = LN(Y)
  ln_simple<false><<<M / 4, 256, 0, stream>>>(Yb, X1b, nullptr);
  // G = relu(X1@W1 + b1), grid 64*24 = 1536
  gemm128<128, 2><<<1536, 256, 0, stream>>>(X1b, W1t, Gb, b1, nullptr, nullptr,
                                            M, H, D);
  // Y2 = G@W2 + b2 + X1 (fused residual), grid 64*8 = 512, nt = 48
  gemm128<96, 3><<<512, 256, 0, stream>>>(Gb, W2t, Y2b, b2, nullptr, X1b, M, D,
                                          H);
  // out = LN(Y2)
  ln_simple<true><<<M / 4, 256, 0, stream>>>(Y2b, nullptr, out);
}